// Round 5
// baseline (165.128 us; speedup 1.0000x reference)
//
#include <hip/hip_runtime.h>
#include <hip/hip_bf16.h>

// FlowNetC correlation via bf16 MFMA, fp32 accumulate.
// out[b, r*21+dx, y, x] = (1/256) * sum_c in1[b,c,y,x] * in2[b,c, y+2r-20, x+2dx-20]
//
// Round-5 structure (async pipelined):
//  1) conv_in2 prepass: in2 fp32 -> in2t bf16 frag-native chunks [b][y][c8][x][c%8];
//     one B-fragment (8 consecutive c at one x) = one 16-B chunk.
//  2) corr_mfma: block = (b, y-pair {y0,y0+2}), 1024 thr / 16 waves, 1 block/CU.
//     Wave w: band tile (m = w&3, n = m + (w>>2)). A-frags for both y's in regs.
//     Pipeline per iter i (in2 row yy = y0-20+2i):
//       - issue global_load_lds DMA of row i+1 -> rowbuf[(i+1)&1]  (in flight
//         across the whole iter; the barrier's vmcnt(0) publishes it)
//       - 8x ds_read_b128 B-frags from rowbuf[i&1] (conflict-free), 16 MFMA
//         (each wfrag feeds both y-halves)
//       - diag gather -> slds[i&1]
//       - ONE __syncthreads()
//       - drain slds[i&1] -> coalesced global stores (overlaps next compute)
//     Round-4 failure mode was barrier/latency serialization at 1 block/CU
//     (44 barriers, loads issued post-barrier): MfmaUtil 12%, VALUBusy 17%.
//     This cuts to 22 barriers and keeps the staging DMA in flight across them.
//
// rowbuf layout: [c8][xp] 16-B chunks, xp = x+20 in [0,112); pads [0,20) and
// [84,112) zeroed once (staging only ever writes [20,84)). Frag read chunk =
// (4k+q)*112 + 16n + cl -> 16-lane groups read 256 B dense: conflict-free.

typedef short    bf16x8 __attribute__((ext_vector_type(8)));
typedef float    f32x4  __attribute__((ext_vector_type(4)));

constexpr int CSTRIDE = 64 * 64;        // fp32 channel plane
constexpr int BSTRIDE = 256 * CSTRIDE;  // fp32 batch
constexpr int CW      = 112;            // padded chunks per c8-row in LDS

union BF2 { __hip_bfloat162 h; unsigned u; };
union BF1 { __hip_bfloat16 h; unsigned short u; };

__device__ inline unsigned pack_bf2(float lo, float hi) {
    BF2 cv;
    cv.h = __float22bfloat162_rn(make_float2(lo, hi));
    return cv.u;
}

// ---------------- prepass: in2 -> bf16 frag-native chunks ----------------
__global__ __launch_bounds__(256)
void conv_in2(const float* __restrict__ in2, unsigned* __restrict__ out_dw)
{
    __shared__ unsigned short lt[64 * 66];   // [x][c_local]
    const int tid = threadIdx.x;
    const int b = blockIdx.x & 7;
    const int y = blockIdx.x >> 3;
    const float* src = in2 + b * BSTRIDE + y * 64;            // + c*4096 + x
    unsigned* odw = out_dw + (b * 64 + y) * 8192;             // 32 KB per (b,y)

    for (int c0 = 0; c0 < 256; c0 += 64) {
        __syncthreads();
#pragma unroll
        for (int it = 0; it < 16; ++it) {
            const int c = it * 4 + (tid >> 6);
            const int x = tid & 63;
            BF1 cv; cv.h = __float2bfloat16(src[(c0 + c) * CSTRIDE + x]);
            lt[x * 66 + c] = cv.u;
        }
        __syncthreads();
        const unsigned* ldw = reinterpret_cast<const unsigned*>(lt);
#pragma unroll
        for (int it = 0; it < 8; ++it) {
            const int d   = tid + 256 * it;   // 0..2047 dwords this c0-chunk
            const int c8g = d >> 8;
            const int x   = (d >> 2) & 63;
            const int cd2 = d & 3;
            odw[((c0 >> 3) + c8g) * 256 + x * 4 + cd2] = ldw[x * 33 + c8g * 4 + cd2];
        }
    }
}

// ---------------- main correlation kernel ----------------
__global__ __launch_bounds__(1024, 4)
void corr_mfma(const float* __restrict__ in1,
               const uint4* __restrict__ in2t,
               float* __restrict__ out)
{
    __shared__ uint4 rowbuf[2][32 * CW];     // 2 x 57,344 B
    __shared__ float slds[2][2][21 * 65];    // [iter-buf][y-half], 21,840 B

    const int tid  = threadIdx.x;
    const int lane = tid & 63;
    const int w    = tid >> 6;          // wave 0..15
    const int cl   = lane & 15;         // MFMA m/n lane index
    const int q    = lane >> 4;         // MFMA quad
    const int m    = w & 3;             // M-tile: gx in [16m, 16m+16)
    const int n    = m + (w >> 2);      // N-tile: col in [16n, 16n+16)
    const int b    = blockIdx.x & 7;    // batch -> XCD affinity
    const int pp   = blockIdx.x >> 3;   // 0..31
    const int y0   = 4 * (pp >> 1) + (pp & 1);   // pair (y0, y0+2)

    // ---- A fragments for both y's: af[h][k] = in1[b, 32k+8q+j, y0+2h, 16m+cl] ----
    bf16x8 af[2][8];
#pragma unroll
    for (int h = 0; h < 2; ++h) {
        const float* pb = in1 + b * BSTRIDE + (y0 + 2 * h) * 64 + 16 * m + cl
                        + 8 * q * CSTRIDE;
#pragma unroll
        for (int k = 0; k < 8; ++k) {
            const float* ppk = pb + 32 * k * CSTRIDE;
            float v[8];
#pragma unroll
            for (int j = 0; j < 8; ++j) v[j] = ppk[j * CSTRIDE];
#pragma unroll
            for (int j = 0; j < 4; ++j)
                ((unsigned*)&af[h][k])[j] = pack_bf2(v[2 * j], v[2 * j + 1]);
        }
    }

    // ---- zero the x-pads once (staging never touches them) ----
    for (int t = tid; t < 2 * 32 * 48; t += 1024) {
        const int bi = t / 1536;
        const int u  = t - bi * 1536;
        const int c8 = u / 48;
        const int j  = u - c8 * 48;
        const int xp = (j < 20) ? j : (j + 64);       // [0,20) or [84,112)
        rowbuf[bi][c8 * CW + xp] = make_uint4(0u, 0u, 0u, 0u);
    }

    // ---- stage row for i=0 (yy = y0-20), if in-bounds ----
    {
        const int yy = y0 - 20;
        if (yy >= 0 && yy < 64) {
#pragma unroll
            for (int j = 0; j < 2; ++j) {
                const int c8 = 2 * w + j;
                const unsigned* g = reinterpret_cast<const unsigned*>(
                    in2t + (b * 64 + yy) * 2048 + c8 * 64 + lane);
                uint4* l = &rowbuf[0][c8 * CW + 20 + lane];
                __builtin_amdgcn_global_load_lds(
                    (const __attribute__((address_space(1))) unsigned*)g,
                    (__attribute__((address_space(3))) unsigned*)l, 16, 0, 0);
            }
        }
    }
    __syncthreads();

    for (int i = 0; i < 22; ++i) {
        const int  yy   = y0 - 20 + 2 * i;
        const bool comp = (yy >= 0) && (yy < 64);
        const int  pb   = i & 1;

        // ---- issue DMA of row i+1 into rowbuf[1-pb]; lands by the barrier ----
        const int yn = yy + 2;
        if (i + 1 < 22 && yn >= 0 && yn < 64) {
#pragma unroll
            for (int j = 0; j < 2; ++j) {
                const int c8 = 2 * w + j;
                const unsigned* g = reinterpret_cast<const unsigned*>(
                    in2t + (b * 64 + yn) * 2048 + c8 * 64 + lane);
                uint4* l = &rowbuf[1 - pb][c8 * CW + 20 + lane];
                __builtin_amdgcn_global_load_lds(
                    (const __attribute__((address_space(1))) unsigned*)g,
                    (__attribute__((address_space(3))) unsigned*)l, 16, 0, 0);
            }
        }

        if (comp) {
            f32x4 acc0 = {0.f, 0.f, 0.f, 0.f};
            f32x4 acc1 = {0.f, 0.f, 0.f, 0.f};
#pragma unroll
            for (int k = 0; k < 8; ++k) {
                const uint4  wv = rowbuf[pb][(4 * k + q) * CW + 16 * n + cl];
                const bf16x8 bf = __builtin_bit_cast(bf16x8, wv);
                acc0 = __builtin_amdgcn_mfma_f32_16x16x32_bf16(af[0][k], bf, acc0, 0, 0, 0);
                acc1 = __builtin_amdgcn_mfma_f32_16x16x32_bf16(af[1][k], bf, acc1, 0, 0, 0);
            }
            // diag gather: gx = 16m+4q+i4, d2 = (16n+cl) - gx = 2*dx
#pragma unroll
            for (int i4 = 0; i4 < 4; ++i4) {
                const int gx = 16 * m + 4 * q + i4;
                const int d2 = (16 * n + cl) - gx;
                if (d2 >= 0 && d2 <= 40 && !(d2 & 1)) {
                    slds[pb][0][(d2 >> 1) * 65 + gx] = acc0[i4];
                    slds[pb][1][(d2 >> 1) * 65 + gx] = acc1[i4];
                }
            }
        }
        __syncthreads();   // publishes: row i+1 DMA, slds[pb] writes

        // ---- drain slds[pb]: half0 -> (y0, r=i), half1 -> (y0+2, r=i-1) ----
        const int r0 = i, r1 = i - 1;
#pragma unroll
        for (int t3 = 0; t3 < 3; ++t3) {
            const int t = tid + 1024 * t3;
            if (t < 2 * 21 * 64) {
                const int h  = (t >= 1344) ? 1 : 0;
                const int u  = t - 1344 * h;
                const int dx = u >> 6, gx = u & 63;
                const int r  = h ? r1 : r0;
                if (r >= 0 && r <= 20) {
                    const float val = comp ? slds[pb][h][dx * 65 + gx] * (1.f / 256.f)
                                           : 0.f;
                    out[((b * 441 + r * 21 + dx) * 64 + y0 + 2 * h) * 64 + gx] = val;
                }
            }
        }
        // no second barrier: next iter writes slds[1-pb] / reads rowbuf[1-pb];
        // this iter's reads complete before the next barrier -> 2-deep buffers safe
    }
}

extern "C" void kernel_launch(void* const* d_in, const int* in_sizes, int n_in,
                              void* d_out, int out_size, void* d_ws, size_t ws_size,
                              hipStream_t stream) {
    const float* in1 = (const float*)d_in[0];
    const float* in2 = (const float*)d_in[1];
    float* out = (float*)d_out;

    conv_in2<<<dim3(512), dim3(256), 0, stream>>>(in2, (unsigned*)d_ws);
    corr_mfma<<<dim3(256), dim3(1024), 0, stream>>>(in1, (const uint4*)d_ws, out);
}